// Round 10
// baseline (182.109 us; speedup 1.0000x reference)
//
#include <hip/hip_runtime.h>

#define BB 16
#define SS 64
#define HH 16
#define DD 16
#define EE 256
#define HIDD 128

typedef float f32x4 __attribute__((ext_vector_type(4)));

#define K2CONST 2.8853900817779268f  /* 2*log2(e) */
#define L2E 1.4426950408889634f

// ---- k1 LDS layout (floats), total 19584 f = 76.5 KB -> 2 blocks/CU ----
#define WQ_OFF 0        // phase1: 16x260 = 4160
#define WK_OFF 4160
#define WV_OFF 8320     // ends 12480
#define EQT_OFF 0       // phase2+: [c][i] 128x65 = 8320 (overlays W region)
#define EKL_OFF 8320    // [j][c] 64x132 = 8448 -> ends 16768
#define QL_OFF 16768    // [i][d] 64x20 (phases 1-2)
#define KL_OFF 18048    // 64x20 -> ends 19328
#define PMX_OFF 16768   // [i][wv] 64x9 (phases 3-4, overlays QL/KL)
#define PSUM_OFF 17344  // 64x9
#define AV2_OFF 19328   // 128
#define KBA_OFF 19456   // 128
#define SM_TOT 19584

// ---------------- k1: per (b,h): q/k/v + pre + scores + softmax -------------
// grid = B*H = 256, block = 512, 2 blocks/CU
__global__ __launch_bounds__(512, 4) void k1(
    const float* __restrict__ x,
    const float* __restrict__ Wq, const float* __restrict__ bq,
    const float* __restrict__ Wk, const float* __restrict__ bk,
    const float* __restrict__ Wv, const float* __restrict__ bv,
    const float* __restrict__ Wa, const float* __restrict__ ba,
    const float* __restrict__ attnv,
    float* __restrict__ v_ws, float* __restrict__ w_ws)
{
  __shared__ float sm[SM_TOT];
  const int t = threadIdx.x;
  const int bid = blockIdx.x;
  const int b = bid >> 4;
  const int h = bid & (HH - 1);

  // ---- stage: W slices (rows h*16..h*16+15), av2, K2*ba ----
  for (int idx = t; idx < 16 * EE; idx += 512) {
    const int r = idx >> 8;
    const int e = idx & 255;
    const size_t g = (size_t)(h * DD + r) * EE + e;
    sm[WQ_OFF + r * 260 + e] = Wq[g];
    sm[WK_OFF + r * 260 + e] = Wk[g];
    sm[WV_OFF + r * 260 + e] = Wv[g];
  }
  if (t < HIDD) {
    sm[AV2_OFF + t] = 2.0f * attnv[t];
    sm[KBA_OFF + t] = K2CONST * ba[t];
  }
  __syncthreads();

  // ---- phase1: q,k,v for row i, cols d and d+8 (head h) ----
  {
    const int i = t >> 3;
    const int dl = t & 7;
    float aq0 = 0.f, aq1 = 0.f, ak0 = 0.f, ak1 = 0.f, av0 = 0.f, av1 = 0.f;
    const float* xr = x + (size_t)(b * SS + i) * EE;
    const float* wq0 = &sm[WQ_OFF + dl * 260];
    const float* wq1 = &sm[WQ_OFF + (dl + 8) * 260];
    const float* wk0 = &sm[WK_OFF + dl * 260];
    const float* wk1 = &sm[WK_OFF + (dl + 8) * 260];
    const float* wv0 = &sm[WV_OFF + dl * 260];
    const float* wv1 = &sm[WV_OFF + (dl + 8) * 260];
#pragma unroll 4
    for (int e = 0; e < EE; e += 4) {
      const f32x4 x4 = *(const f32x4*)(xr + e);
      const f32x4 q04 = *(const f32x4*)(wq0 + e);
      const f32x4 q14 = *(const f32x4*)(wq1 + e);
      const f32x4 k04 = *(const f32x4*)(wk0 + e);
      const f32x4 k14 = *(const f32x4*)(wk1 + e);
      const f32x4 v04 = *(const f32x4*)(wv0 + e);
      const f32x4 v14 = *(const f32x4*)(wv1 + e);
#pragma unroll
      for (int u = 0; u < 4; ++u) {
        aq0 = fmaf(x4[u], q04[u], aq0);
        aq1 = fmaf(x4[u], q14[u], aq1);
        ak0 = fmaf(x4[u], k04[u], ak0);
        ak1 = fmaf(x4[u], k14[u], ak1);
        av0 = fmaf(x4[u], v04[u], av0);
        av1 = fmaf(x4[u], v14[u], av1);
      }
    }
    sm[QL_OFF + i * 20 + dl]     = aq0 + bq[h * DD + dl];
    sm[QL_OFF + i * 20 + dl + 8] = aq1 + bq[h * DD + dl + 8];
    sm[KL_OFF + i * 20 + dl]     = ak0 + bk[h * DD + dl];
    sm[KL_OFF + i * 20 + dl + 8] = ak1 + bk[h * DD + dl + 8];
    v_ws[(size_t)(b * SS + i) * EE + h * DD + dl]     = av0 + bv[h * DD + dl];
    v_ws[(size_t)(b * SS + i) * EE + h * DD + dl + 8] = av1 + bv[h * DD + dl + 8];
  }
  __syncthreads();

  // ---- phase2: eq[c][i], ek[j][c] (Wa, scaled by K2, exp2'd). Wa from global.
  {
    const int i = t >> 3;
    const int cg = t & 7;
    f32x4 q4[4], k4[4];
#pragma unroll
    for (int u = 0; u < 4; ++u) {
      q4[u] = *(const f32x4*)&sm[QL_OFF + i * 20 + u * 4];
      k4[u] = *(const f32x4*)&sm[KL_OFF + i * 20 + u * 4];
    }
#pragma unroll 2
    for (int jj = 0; jj < 16; ++jj) {
      const int c = cg + 8 * jj;
      const f32x4* war = (const f32x4*)(Wa + (size_t)c * 32);
      float sq = 0.f, sk = 0.f;
#pragma unroll
      for (int u = 0; u < 4; ++u) {
        const f32x4 a4 = war[u];
        const f32x4 b4 = war[4 + u];
#pragma unroll
        for (int w = 0; w < 4; ++w) {
          sq = fmaf(q4[u][w], a4[w], sq);
          sk = fmaf(k4[u][w], b4[w], sk);
        }
      }
      const float eq = __builtin_amdgcn_exp2f(fmaf(K2CONST, sq, sm[KBA_OFF + c]));
      const float ek = __builtin_amdgcn_exp2f(K2CONST * sk);
      sm[EQT_OFF + c * 65 + i] = eq;
      sm[EKL_OFF + i * 132 + c] = ek;
    }
  }
  __syncthreads();

  // ---- phase3: scores + register softmax + transposed coalesced write ----
  {
    const int i = t & 63;
    const int wv = t >> 6;
    const int j0 = wv << 3;
    float acc[8];
#pragma unroll
    for (int jj = 0; jj < 8; ++jj) acc[jj] = 0.f;
#pragma unroll 2
    for (int c = 0; c < HIDD; c += 4) {
      const f32x4 a4 = *(const f32x4*)&sm[AV2_OFF + c];
      float eq[4];
#pragma unroll
      for (int u = 0; u < 4; ++u) eq[u] = sm[EQT_OFF + (c + u) * 65 + i];
      f32x4 ek[8];
#pragma unroll
      for (int jj = 0; jj < 8; ++jj) ek[jj] = *(const f32x4*)&sm[EKL_OFF + (j0 + jj) * 132 + c];
#pragma unroll
      for (int u = 0; u < 4; ++u) {
#pragma unroll
        for (int jj = 0; jj < 8; ++jj) {
          const float r = __builtin_amdgcn_rcpf(fmaf(eq[u], ek[jj][u], 1.f));
          acc[jj] = fmaf(a4[u], r, acc[jj]);
        }
      }
    }
    // scores s[jj] = -acc[jj]; softmax over all 64 j (8 waves x 8)
    float lm = -acc[0];
#pragma unroll
    for (int jj = 1; jj < 8; ++jj) lm = fmaxf(lm, -acc[jj]);
    sm[PMX_OFF + i * 9 + wv] = lm;
    __syncthreads();
    float gm = sm[PMX_OFF + i * 9];
#pragma unroll
    for (int w = 1; w < 8; ++w) gm = fmaxf(gm, sm[PMX_OFF + i * 9 + w]);
    float p[8], ls = 0.f;
#pragma unroll
    for (int jj = 0; jj < 8; ++jj) {
      p[jj] = __builtin_amdgcn_exp2f((-acc[jj] - gm) * L2E);
      ls += p[jj];
    }
    sm[PSUM_OFF + i * 9 + wv] = ls;
    __syncthreads();
    float tot = sm[PSUM_OFF + i * 9];
#pragma unroll
    for (int w = 1; w < 8; ++w) tot += sm[PSUM_OFF + i * 9 + w];
    const float rs = __builtin_amdgcn_rcpf(tot);
    // w_ws layout [b][h][j][i]: lane i consecutive -> coalesced
#pragma unroll
    for (int jj = 0; jj < 8; ++jj)
      w_ws[((size_t)bid * SS + j0 + jj) * SS + i] = p[jj] * rs;
  }
}

// ---------------- k2: ctx (contract heads) + fc GEMV ------------------------
// grid = B*S/4 = 256, block = 512. fc: p-outer / e-inner for 8x ctx reuse.
__global__ __launch_bounds__(512) void k2(
    const float* __restrict__ w_ws, const float* __restrict__ v_ws,
    const float* __restrict__ Wfc, const float* __restrict__ bfc,
    float* __restrict__ out)
{
  __shared__ float wl[4 * 1024];   // [r][h*64+j]
  __shared__ float vl[4 * 272];    // [r][h*17+d]
  __shared__ float ctx[4 * 1024];  // [r][j*16+d]
  const int t = threadIdx.x;
  const int row0 = blockIdx.x * 4;
  const int b = row0 >> 6;
  const int i0 = row0 & 63;

  // w_ws is [b][h][j][i]: b128 over i gives all 4 rows at once
#pragma unroll
  for (int u = 0; u < 2; ++u) {
    const int idx = t + 512 * u;
    const int hh = idx >> 6;
    const int j = idx & 63;
    const f32x4 v4 = *(const f32x4*)&w_ws[(((size_t)b * HH + hh) * SS + j) * SS + i0];
    wl[0 * 1024 + hh * 64 + j] = v4[0];
    wl[1 * 1024 + hh * 64 + j] = v4[1];
    wl[2 * 1024 + hh * 64 + j] = v4[2];
    wl[3 * 1024 + hh * 64 + j] = v4[3];
  }
#pragma unroll
  for (int u = 0; u < 2; ++u) {
    const int idx = t + 512 * u;
    const int r = idx >> 8;
    const int rem = idx & 255;
    vl[r * 272 + (rem >> 4) * 17 + (rem & 15)] = v_ws[(size_t)(row0 + r) * EE + rem];
  }
  __syncthreads();

  // ctx[r][j*16+d] = sum_h wl[r][h][j] * vl[r][h][d]
#pragma unroll
  for (int u = 0; u < 8; ++u) {
    const int o = t + 512 * u;
    const int r = o >> 10;
    const int rem = o & 1023;
    const int j = rem >> 4;
    const int d = rem & 15;
    float s = 0.f;
#pragma unroll
    for (int hh = 0; hh < HH; ++hh)
      s = fmaf(wl[r * 1024 + hh * 64 + j], vl[r * 272 + hh * 17 + d], s);
    ctx[o] = s;
  }
  __syncthreads();

  // fc: thread (kg = lane&15 k-chunk, eg = lane>>4, wave) -> 8 e-cols x 4 rows
  {
    const int lane = t & 63;
    const int wave = t >> 6;
    const int kg = lane & 15;
    const int eg = lane >> 4;
    float acc[8][4];
#pragma unroll
    for (int off = 0; off < 8; ++off)
#pragma unroll
      for (int r = 0; r < 4; ++r) acc[off][r] = 0.f;

    for (int p = 0; p < 16; ++p) {
      const int k0 = p * 64 + kg * 4;
      const f32x4 c0 = *(const f32x4*)(ctx + k0);
      const f32x4 c1 = *(const f32x4*)(ctx + 1024 + k0);
      const f32x4 c2 = *(const f32x4*)(ctx + 2048 + k0);
      const f32x4 c3 = *(const f32x4*)(ctx + 3072 + k0);
#pragma unroll
      for (int off = 0; off < 8; ++off) {
        const int e = wave * 32 + off * 4 + eg;
        const f32x4 wf = *(const f32x4*)&Wfc[(size_t)e * (SS * DD) + k0];
#pragma unroll
        for (int u = 0; u < 4; ++u) {
          acc[off][0] = fmaf(wf[u], c0[u], acc[off][0]);
          acc[off][1] = fmaf(wf[u], c1[u], acc[off][1]);
          acc[off][2] = fmaf(wf[u], c2[u], acc[off][2]);
          acc[off][3] = fmaf(wf[u], c3[u], acc[off][3]);
        }
      }
    }
    // reduce over kg (16 lanes)
#pragma unroll
    for (int off = 0; off < 8; ++off)
#pragma unroll
      for (int r = 0; r < 4; ++r) {
#pragma unroll
        for (int msk = 1; msk <= 8; msk <<= 1)
          acc[off][r] += __shfl_xor(acc[off][r], msk);
      }
    if (kg == 0) {
#pragma unroll
      for (int off = 0; off < 8; ++off) {
        const int e = wave * 32 + off * 4 + eg;
        const float bias = bfc[e];
#pragma unroll
        for (int r = 0; r < 4; ++r)
          out[(size_t)(row0 + r) * EE + e] = acc[off][r] + bias;
      }
    }
  }
}

extern "C" void kernel_launch(void* const* d_in, const int* in_sizes, int n_in,
                              void* d_out, int out_size, void* d_ws, size_t ws_size,
                              hipStream_t stream) {
  const float* x   = (const float*)d_in[0];
  const float* Wq  = (const float*)d_in[1];
  const float* bq  = (const float*)d_in[2];
  const float* Wk  = (const float*)d_in[3];
  const float* bk  = (const float*)d_in[4];
  const float* Wv  = (const float*)d_in[5];
  const float* bv  = (const float*)d_in[6];
  const float* Wa  = (const float*)d_in[7];
  const float* ba  = (const float*)d_in[8];
  const float* av  = (const float*)d_in[9];
  const float* Wfc = (const float*)d_in[10];
  const float* bfc = (const float*)d_in[11];

  float* ws = (float*)d_ws;
  float* v_ws = ws;                                 // B*S*E   = 262144 f32
  float* w_ws = v_ws + (size_t)BB * SS * EE;        // B*H*S*S = 1048576 f32 ([b][h][j][i])

  hipLaunchKernelGGL(k1, dim3(BB * HH), dim3(512), 0, stream,
                     x, Wq, bq, Wk, bk, Wv, bv, Wa, ba, av, v_ws, w_ws);
  hipLaunchKernelGGL(k2, dim3(BB * SS / 4), dim3(512), 0, stream,
                     w_ws, v_ws, Wfc, bfc, (float*)d_out);
}

// Round 11
// 158.584 us; speedup vs baseline: 1.1483x; 1.1483x over previous
//
#include <hip/hip_runtime.h>

#define BB 16
#define SS 64
#define HH 16
#define DD 16
#define EE 256
#define HIDD 128

typedef float f32x4 __attribute__((ext_vector_type(4)));

#define K2CONST 2.8853900817779268f  /* 2*log2(e) */
#define L2E 1.4426950408889634f

// ---- k1 LDS layout (floats), total 19584 f = 76.5 KB -> 2 blocks/CU ----
#define WQ_OFF 0        // phase1: 16x260 = 4160
#define WK_OFF 4160
#define WV_OFF 8320     // ends 12480
#define EQT_OFF 0       // phase2+: [c][i] 128x65 = 8320 (overlays W region)
#define EKL_OFF 8320    // [j][c] 64x132 = 8448 -> ends 16768
#define QL_OFF 16768    // [i][d] 64x20 (phases 1-2)
#define KL_OFF 18048    // 64x20 -> ends 19328
#define PMX_OFF 16768   // [i][wv] 64x9 (phase 3, overlays QL/KL)
#define PSUM_OFF 17344  // 64x9
#define AV2_OFF 19328   // 128
#define KBA_OFF 19456   // 128
#define SM_TOT 19584

// ---------------- k1: per (b,h): q/k/v + pre + scores + softmax -------------
// grid = B*H = 256, block = 512. NO min-waves hint (round-10 lesson: it
// squeezed VGPR 88->64 and spilled phase3; 88 VGPR still allows 16 waves/CU).
__global__ __launch_bounds__(512) void k1(
    const float* __restrict__ x,
    const float* __restrict__ Wq, const float* __restrict__ bq,
    const float* __restrict__ Wk, const float* __restrict__ bk,
    const float* __restrict__ Wv, const float* __restrict__ bv,
    const float* __restrict__ Wa, const float* __restrict__ ba,
    const float* __restrict__ attnv,
    float* __restrict__ v_ws, float* __restrict__ w_ws)
{
  __shared__ float sm[SM_TOT];
  const int t = threadIdx.x;
  const int bid = blockIdx.x;
  const int b = bid >> 4;
  const int h = bid & (HH - 1);

  for (int idx = t; idx < 16 * EE; idx += 512) {
    const int r = idx >> 8;
    const int e = idx & 255;
    const size_t g = (size_t)(h * DD + r) * EE + e;
    sm[WQ_OFF + r * 260 + e] = Wq[g];
    sm[WK_OFF + r * 260 + e] = Wk[g];
    sm[WV_OFF + r * 260 + e] = Wv[g];
  }
  if (t < HIDD) {
    sm[AV2_OFF + t] = 2.0f * attnv[t];
    sm[KBA_OFF + t] = K2CONST * ba[t];
  }
  __syncthreads();

  // ---- phase1: q,k,v for row i, cols d and d+8 (head h) ----
  {
    const int i = t >> 3;
    const int dl = t & 7;
    float aq0 = 0.f, aq1 = 0.f, ak0 = 0.f, ak1 = 0.f, av0 = 0.f, av1 = 0.f;
    const float* xr = x + (size_t)(b * SS + i) * EE;
    const float* wq0 = &sm[WQ_OFF + dl * 260];
    const float* wq1 = &sm[WQ_OFF + (dl + 8) * 260];
    const float* wk0 = &sm[WK_OFF + dl * 260];
    const float* wk1 = &sm[WK_OFF + (dl + 8) * 260];
    const float* wv0 = &sm[WV_OFF + dl * 260];
    const float* wv1 = &sm[WV_OFF + (dl + 8) * 260];
#pragma unroll 4
    for (int e = 0; e < EE; e += 4) {
      const f32x4 x4 = *(const f32x4*)(xr + e);
      const f32x4 q04 = *(const f32x4*)(wq0 + e);
      const f32x4 q14 = *(const f32x4*)(wq1 + e);
      const f32x4 k04 = *(const f32x4*)(wk0 + e);
      const f32x4 k14 = *(const f32x4*)(wk1 + e);
      const f32x4 v04 = *(const f32x4*)(wv0 + e);
      const f32x4 v14 = *(const f32x4*)(wv1 + e);
#pragma unroll
      for (int u = 0; u < 4; ++u) {
        aq0 = fmaf(x4[u], q04[u], aq0);
        aq1 = fmaf(x4[u], q14[u], aq1);
        ak0 = fmaf(x4[u], k04[u], ak0);
        ak1 = fmaf(x4[u], k14[u], ak1);
        av0 = fmaf(x4[u], v04[u], av0);
        av1 = fmaf(x4[u], v14[u], av1);
      }
    }
    sm[QL_OFF + i * 20 + dl]     = aq0 + bq[h * DD + dl];
    sm[QL_OFF + i * 20 + dl + 8] = aq1 + bq[h * DD + dl + 8];
    sm[KL_OFF + i * 20 + dl]     = ak0 + bk[h * DD + dl];
    sm[KL_OFF + i * 20 + dl + 8] = ak1 + bk[h * DD + dl + 8];
    v_ws[(size_t)(b * SS + i) * EE + h * DD + dl]     = av0 + bv[h * DD + dl];
    v_ws[(size_t)(b * SS + i) * EE + h * DD + dl + 8] = av1 + bv[h * DD + dl + 8];
  }
  __syncthreads();

  // ---- phase2: eq[c][i], ek[j][c]; Wa read from global (L2 broadcast) ----
  {
    const int i = t >> 3;
    const int cg = t & 7;
    f32x4 q4[4], k4[4];
#pragma unroll
    for (int u = 0; u < 4; ++u) {
      q4[u] = *(const f32x4*)&sm[QL_OFF + i * 20 + u * 4];
      k4[u] = *(const f32x4*)&sm[KL_OFF + i * 20 + u * 4];
    }
#pragma unroll 2
    for (int jj = 0; jj < 16; ++jj) {
      const int c = cg + 8 * jj;
      const f32x4* war = (const f32x4*)(Wa + (size_t)c * 32);
      float sq = 0.f, sk = 0.f;
#pragma unroll
      for (int u = 0; u < 4; ++u) {
        const f32x4 a4 = war[u];
        const f32x4 b4 = war[4 + u];
#pragma unroll
        for (int w = 0; w < 4; ++w) {
          sq = fmaf(q4[u][w], a4[w], sq);
          sk = fmaf(k4[u][w], b4[w], sk);
        }
      }
      const float eq = __builtin_amdgcn_exp2f(fmaf(K2CONST, sq, sm[KBA_OFF + c]));
      const float ek = __builtin_amdgcn_exp2f(K2CONST * sk);
      sm[EQT_OFF + c * 65 + i] = eq;
      sm[EKL_OFF + i * 132 + c] = ek;
    }
  }
  __syncthreads();

  // ---- phase3: scores + cross-wave softmax + coalesced [b][h][j][i] write --
  {
    const int i = t & 63;
    const int wv = t >> 6;
    const int j0 = wv << 3;
    float acc[8];
#pragma unroll
    for (int jj = 0; jj < 8; ++jj) acc[jj] = 0.f;
#pragma unroll 2
    for (int c = 0; c < HIDD; c += 4) {
      const f32x4 a4 = *(const f32x4*)&sm[AV2_OFF + c];
      float eq[4];
#pragma unroll
      for (int u = 0; u < 4; ++u) eq[u] = sm[EQT_OFF + (c + u) * 65 + i];
      f32x4 ek[8];
#pragma unroll
      for (int jj = 0; jj < 8; ++jj) ek[jj] = *(const f32x4*)&sm[EKL_OFF + (j0 + jj) * 132 + c];
#pragma unroll
      for (int u = 0; u < 4; ++u) {
#pragma unroll
        for (int jj = 0; jj < 8; ++jj) {
          const float r = __builtin_amdgcn_rcpf(fmaf(eq[u], ek[jj][u], 1.f));
          acc[jj] = fmaf(a4[u], r, acc[jj]);
        }
      }
    }
    float lm = -acc[0];
#pragma unroll
    for (int jj = 1; jj < 8; ++jj) lm = fmaxf(lm, -acc[jj]);
    sm[PMX_OFF + i * 9 + wv] = lm;
    __syncthreads();
    float gm = sm[PMX_OFF + i * 9];
#pragma unroll
    for (int w = 1; w < 8; ++w) gm = fmaxf(gm, sm[PMX_OFF + i * 9 + w]);
    float p[8], ls = 0.f;
#pragma unroll
    for (int jj = 0; jj < 8; ++jj) {
      p[jj] = __builtin_amdgcn_exp2f((-acc[jj] - gm) * L2E);
      ls += p[jj];
    }
    sm[PSUM_OFF + i * 9 + wv] = ls;
    __syncthreads();
    float tot = sm[PSUM_OFF + i * 9];
#pragma unroll
    for (int w = 1; w < 8; ++w) tot += sm[PSUM_OFF + i * 9 + w];
    const float rs = __builtin_amdgcn_rcpf(tot);
#pragma unroll
    for (int jj = 0; jj < 8; ++jj)
      w_ws[((size_t)bid * SS + j0 + jj) * SS + i] = p[jj] * rs;
  }
}

// ---------------- k2a: ctx only -> ctx_ws[row][1024] ------------------------
// grid = 256 (4 rows/block), block = 512
__global__ __launch_bounds__(512) void k2a(
    const float* __restrict__ w_ws, const float* __restrict__ v_ws,
    float* __restrict__ ctx_ws)
{
  __shared__ float wl[4 * 1024];   // [r][h*64+j]
  __shared__ float vl[4 * 272];    // [r][h*17+d]
  const int t = threadIdx.x;
  const int row0 = blockIdx.x * 4;
  const int b = row0 >> 6;
  const int i0 = row0 & 63;

  // w_ws is [b][h][j][i]: f32x4 over i gives all 4 rows at once
#pragma unroll
  for (int u = 0; u < 2; ++u) {
    const int idx = t + 512 * u;
    const int hh = idx >> 6;
    const int j = idx & 63;
    const f32x4 v4 = *(const f32x4*)&w_ws[(((size_t)b * HH + hh) * SS + j) * SS + i0];
    wl[0 * 1024 + hh * 64 + j] = v4[0];
    wl[1 * 1024 + hh * 64 + j] = v4[1];
    wl[2 * 1024 + hh * 64 + j] = v4[2];
    wl[3 * 1024 + hh * 64 + j] = v4[3];
  }
#pragma unroll
  for (int u = 0; u < 2; ++u) {
    const int idx = t + 512 * u;
    const int r = idx >> 8;
    const int rem = idx & 255;
    vl[r * 272 + (rem >> 4) * 17 + (rem & 15)] = v_ws[(size_t)(row0 + r) * EE + rem];
  }
  __syncthreads();

  // ctx[row0+r][j*16+d] = sum_h wl[r][h][j] * vl[r][h][d]  (coalesced write)
#pragma unroll
  for (int u = 0; u < 8; ++u) {
    const int o = t + 512 * u;
    const int r = o >> 10;
    const int rem = o & 1023;
    const int j = rem >> 4;
    const int d = rem & 15;
    float s = 0.f;
#pragma unroll
    for (int hh = 0; hh < HH; ++hh)
      s = fmaf(wl[r * 1024 + hh * 64 + j], vl[r * 272 + hh * 17 + d], s);
    ctx_ws[(size_t)(row0 + r) * 1024 + rem] = s;
  }
}

// ---------------- k2b: GEMM out[1024,256] = ctx @ Wfc^T + bfc ---------------
// grid = dim3(16,16): bx = e-tile (16 e), by = row-tile (64 rows). 256 thr.
// Thread: tile = t>>2 (rg = tile>>3 of 8 rows, eg = tile&7 of 2 e), ks = t&3
// (k-split interleaved at f32x4 granularity). acc[8][2], reduce via shfl.
#define KCH 128
__global__ __launch_bounds__(256) void k2b(
    const float* __restrict__ ctx_ws, const float* __restrict__ Wfc,
    const float* __restrict__ bfc, float* __restrict__ out)
{
  __shared__ __align__(16) float As[64 * 132];  // [row][k] stride 132
  __shared__ __align__(16) float Bs[16 * 132];  // [e][k]
  const int t = threadIdx.x;
  const int e0 = blockIdx.x * 16;
  const int row0 = blockIdx.y * 64;
  const int tile = t >> 2;
  const int ks = t & 3;
  const int rg = tile >> 3;      // 0..7 -> rows rg*8..rg*8+7
  const int eg = tile & 7;       // 0..7 -> e eg*2, eg*2+1

  float acc[8][2];
#pragma unroll
  for (int r = 0; r < 8; ++r) { acc[r][0] = 0.f; acc[r][1] = 0.f; }

  for (int kc = 0; kc < 1024; kc += KCH) {
    // stage A: 64 rows x 128 k  (2048 f32x4, 8 per thread, coalesced)
#pragma unroll
    for (int u = 0; u < 8; ++u) {
      const int idx = t + 256 * u;
      const int r = idx >> 5;
      const int kq = (idx & 31) << 2;
      *(f32x4*)&As[r * 132 + kq] =
          *(const f32x4*)&ctx_ws[(size_t)(row0 + r) * 1024 + kc + kq];
    }
    // stage B: 16 e x 128 k (512 f32x4, 2 per thread)
#pragma unroll
    for (int u = 0; u < 2; ++u) {
      const int idx = t + 256 * u;
      const int e = idx >> 5;
      const int kq = (idx & 31) << 2;
      *(f32x4*)&Bs[e * 132 + kq] =
          *(const f32x4*)&Wfc[(size_t)(e0 + e) * 1024 + kc + kq];
    }
    __syncthreads();

#pragma unroll
    for (int kk = 0; kk < 8; ++kk) {
      const int kb = kk * 16 + ks * 4;  // ks interleave -> distinct banks
      const f32x4 b0 = *(const f32x4*)&Bs[(eg * 2 + 0) * 132 + kb];
      const f32x4 b1 = *(const f32x4*)&Bs[(eg * 2 + 1) * 132 + kb];
#pragma unroll
      for (int r = 0; r < 8; ++r) {
        const f32x4 a = *(const f32x4*)&As[(rg * 8 + r) * 132 + kb];
#pragma unroll
        for (int u = 0; u < 4; ++u) {
          acc[r][0] = fmaf(a[u], b0[u], acc[r][0]);
          acc[r][1] = fmaf(a[u], b1[u], acc[r][1]);
        }
      }
    }
    __syncthreads();
  }

  // reduce over ks (4 consecutive lanes = same tile)
#pragma unroll
  for (int r = 0; r < 8; ++r) {
#pragma unroll
    for (int e = 0; e < 2; ++e) {
      acc[r][e] += __shfl_xor(acc[r][e], 1);
      acc[r][e] += __shfl_xor(acc[r][e], 2);
    }
  }
  if (ks == 0) {
    const float bia0 = bfc[e0 + eg * 2];
    const float bia1 = bfc[e0 + eg * 2 + 1];
#pragma unroll
    for (int r = 0; r < 8; ++r) {
      const size_t o = (size_t)(row0 + rg * 8 + r) * EE + e0 + eg * 2;
      out[o]     = acc[r][0] + bia0;
      out[o + 1] = acc[r][1] + bia1;
    }
  }
}

extern "C" void kernel_launch(void* const* d_in, const int* in_sizes, int n_in,
                              void* d_out, int out_size, void* d_ws, size_t ws_size,
                              hipStream_t stream) {
  const float* x   = (const float*)d_in[0];
  const float* Wq  = (const float*)d_in[1];
  const float* bq  = (const float*)d_in[2];
  const float* Wk  = (const float*)d_in[3];
  const float* bk  = (const float*)d_in[4];
  const float* Wv  = (const float*)d_in[5];
  const float* bv  = (const float*)d_in[6];
  const float* Wa  = (const float*)d_in[7];
  const float* ba  = (const float*)d_in[8];
  const float* av  = (const float*)d_in[9];
  const float* Wfc = (const float*)d_in[10];
  const float* bfc = (const float*)d_in[11];

  float* ws = (float*)d_ws;
  float* v_ws   = ws;                                   // 262144 f32
  float* w_ws   = v_ws + (size_t)BB * SS * EE;          // 1048576 f32 [b][h][j][i]
  float* ctx_ws = w_ws + (size_t)BB * HH * SS * SS;     // 1048576 f32 [row][m]

  hipLaunchKernelGGL(k1, dim3(BB * HH), dim3(512), 0, stream,
                     x, Wq, bq, Wk, bk, Wv, bv, Wa, ba, av, v_ws, w_ws);
  hipLaunchKernelGGL(k2a, dim3(BB * SS / 4), dim3(512), 0, stream,
                     w_ws, v_ws, ctx_ws);
  hipLaunchKernelGGL(k2b, dim3(16, 16), dim3(256), 0, stream,
                     ctx_ws, Wfc, bfc, (float*)d_out);
}

// Round 12
// 154.428 us; speedup vs baseline: 1.1793x; 1.0269x over previous
//
#include <hip/hip_runtime.h>

#define BB 16
#define SS 64
#define HH 16
#define DD 16
#define EE 256
#define HIDD 128

typedef float f32x4 __attribute__((ext_vector_type(4)));

#define K2CONST 2.8853900817779268f  /* 2*log2(e) */
#define L2E 1.4426950408889634f

// ---- k1 LDS layout (floats), total 14848 f = 58 KB -> 2 blocks/CU ----
#define WQ_OFF 0        // phase1: 16x260 = 4160
#define WK_OFF 4160
#define WV_OFF 8320     // ends 12480 (dead after phase1)
#define EQT_OFF 0       // phase2+: [c][il] 128x33 = 4224 (overlays W)
#define EKL_OFF 4224    // [j][c] 64x132 = 8448 -> ends 12672
#define QL_OFF 12672    // [il][d] 32x20 = 640
#define KL_OFF 13312    // [j][d] 64x20 = 1280 -> ends 14592
#define PMX_OFF 12672   // [il][slot] 32x17 = 544 (phase3, overlays QL)
#define PSUM_OFF 13216  // 544 -> ends 13760
#define AV2_OFF 14592   // 128
#define KBA_OFF 14720   // 128
#define SM_TOT 14848

// ---- k1: per (b,h,i-half): q/k/v + pre + scores + softmax ------------------
// grid = B*H*2 = 512 (2 blocks/CU), block = 512 (8 waves)
__global__ __launch_bounds__(512) void k1(
    const float* __restrict__ x,
    const float* __restrict__ Wq, const float* __restrict__ bq,
    const float* __restrict__ Wk, const float* __restrict__ bk,
    const float* __restrict__ Wv, const float* __restrict__ bv,
    const float* __restrict__ Wa, const float* __restrict__ ba,
    const float* __restrict__ attnv,
    float* __restrict__ v_ws, float* __restrict__ w_ws)
{
  __shared__ float sm[SM_TOT];
  const int t = threadIdx.x;
  const int bid = blockIdx.x;
  const int bh = bid >> 1;
  const int half = bid & 1;
  const int b = bh >> 4;
  const int h = bh & (HH - 1);
  const int i0 = half << 5;  // this block's query rows: i0..i0+31

  // stage W slices (head h rows) into LDS; av2, K2*ba
  for (int idx = t; idx < 16 * EE; idx += 512) {
    const int r = idx >> 8;
    const int e = idx & 255;
    const size_t g = (size_t)(h * DD + r) * EE + e;
    sm[WQ_OFF + r * 260 + e] = Wq[g];
    sm[WK_OFF + r * 260 + e] = Wk[g];
    sm[WV_OFF + r * 260 + e] = Wv[g];
  }
  if (t < HIDD) {
    sm[AV2_OFF + t] = 2.0f * attnv[t];
    sm[KBA_OFF + t] = K2CONST * ba[t];
  }
  __syncthreads();

  // ---- phase1: q,v for rows i0+r16; k for rows r16 and r16+32 (all j) ----
  {
    const int r16 = t >> 4;   // 0..31
    const int dl = t & 15;    // output col
    const float* xa = x + (size_t)(b * SS + r16) * EE;
    const float* xb = xa + 32 * EE;
    const float* wq = &sm[WQ_OFF + dl * 260];
    const float* wk = &sm[WK_OFF + dl * 260];
    const float* wv = &sm[WV_OFF + dl * 260];
    float aq = 0.f, av = 0.f, ak0 = 0.f, ak1 = 0.f;
#pragma unroll 4
    for (int e = 0; e < EE; e += 4) {
      const f32x4 a4 = *(const f32x4*)(xa + e);
      const f32x4 b4 = *(const f32x4*)(xb + e);
      const f32x4 i4 = half ? b4 : a4;
      const f32x4 q4 = *(const f32x4*)(wq + e);
      const f32x4 k4 = *(const f32x4*)(wk + e);
      const f32x4 v4 = *(const f32x4*)(wv + e);
#pragma unroll
      for (int u = 0; u < 4; ++u) {
        aq = fmaf(i4[u], q4[u], aq);
        av = fmaf(i4[u], v4[u], av);
        ak0 = fmaf(a4[u], k4[u], ak0);
        ak1 = fmaf(b4[u], k4[u], ak1);
      }
    }
    sm[QL_OFF + r16 * 20 + dl] = aq + bq[h * DD + dl];
    sm[KL_OFF + r16 * 20 + dl] = ak0 + bk[h * DD + dl];
    sm[KL_OFF + (r16 + 32) * 20 + dl] = ak1 + bk[h * DD + dl];
    v_ws[(size_t)(b * SS + i0 + r16) * EE + h * DD + dl] = av + bv[h * DD + dl];
  }
  __syncthreads();

  // ---- phase2: eq[c][il] (32 i), ek[j][c] (64 j); Wa from global ----
  {
    const int i16 = t >> 4;   // 0..31
    const int cg = t & 15;
    // eq part first (q regs die before k regs load -> low pressure)
    {
      f32x4 q4[4];
#pragma unroll
      for (int u = 0; u < 4; ++u) q4[u] = *(const f32x4*)&sm[QL_OFF + i16 * 20 + u * 4];
#pragma unroll 2
      for (int jj = 0; jj < 8; ++jj) {
        const int c = cg + 16 * jj;
        const f32x4* war = (const f32x4*)(Wa + (size_t)c * 32);
        float sq = 0.f;
#pragma unroll
        for (int u = 0; u < 4; ++u) {
          const f32x4 a4 = war[u];
#pragma unroll
          for (int w = 0; w < 4; ++w) sq = fmaf(q4[u][w], a4[w], sq);
        }
        sm[EQT_OFF + c * 33 + i16] =
            __builtin_amdgcn_exp2f(fmaf(K2CONST, sq, sm[KBA_OFF + c]));
      }
    }
    // ek part: rows j = i16 and i16+32
    {
      f32x4 k4a[4], k4b[4];
#pragma unroll
      for (int u = 0; u < 4; ++u) {
        k4a[u] = *(const f32x4*)&sm[KL_OFF + i16 * 20 + u * 4];
        k4b[u] = *(const f32x4*)&sm[KL_OFF + (i16 + 32) * 20 + u * 4];
      }
#pragma unroll 2
      for (int jj = 0; jj < 8; ++jj) {
        const int c = cg + 16 * jj;
        const f32x4* war = (const f32x4*)(Wa + (size_t)c * 32 + 16);
        float sa = 0.f, sb = 0.f;
#pragma unroll
        for (int u = 0; u < 4; ++u) {
          const f32x4 b4 = war[u];
#pragma unroll
          for (int w = 0; w < 4; ++w) {
            sa = fmaf(k4a[u][w], b4[w], sa);
            sb = fmaf(k4b[u][w], b4[w], sb);
          }
        }
        sm[EKL_OFF + i16 * 132 + c] = __builtin_amdgcn_exp2f(K2CONST * sa);
        sm[EKL_OFF + (i16 + 32) * 132 + c] = __builtin_amdgcn_exp2f(K2CONST * sb);
      }
    }
  }
  __syncthreads();

  // ---- phase3: scores (4 j per thread -> low VGPR) + softmax + write ----
  {
    const int l = t & 63;
    const int il = l & 31;         // local query row
    const int jh = l >> 5;         // 0/1: j-half within wave
    const int w = t >> 6;          // wave 0..7
    const int j0 = w * 4 + jh * 32;
    const int slot = (t >> 5) & 15;  // = w*2 + jh
    float acc[4];
#pragma unroll
    for (int jj = 0; jj < 4; ++jj) acc[jj] = 0.f;
#pragma unroll 2
    for (int c = 0; c < HIDD; c += 4) {
      const f32x4 a4 = *(const f32x4*)&sm[AV2_OFF + c];
      float eq[4];
#pragma unroll
      for (int u = 0; u < 4; ++u) eq[u] = sm[EQT_OFF + (c + u) * 33 + il];
      f32x4 ek[4];
#pragma unroll
      for (int jj = 0; jj < 4; ++jj) ek[jj] = *(const f32x4*)&sm[EKL_OFF + (j0 + jj) * 132 + c];
#pragma unroll
      for (int u = 0; u < 4; ++u) {
#pragma unroll
        for (int jj = 0; jj < 4; ++jj) {
          const float r = __builtin_amdgcn_rcpf(fmaf(eq[u], ek[jj][u], 1.f));
          acc[jj] = fmaf(a4[u], r, acc[jj]);
        }
      }
    }
    float lm = -acc[0];
#pragma unroll
    for (int jj = 1; jj < 4; ++jj) lm = fmaxf(lm, -acc[jj]);
    sm[PMX_OFF + il * 17 + slot] = lm;
    __syncthreads();
    float gm = sm[PMX_OFF + il * 17];
#pragma unroll
    for (int s = 1; s < 16; ++s) gm = fmaxf(gm, sm[PMX_OFF + il * 17 + s]);
    float p[4], ls = 0.f;
#pragma unroll
    for (int jj = 0; jj < 4; ++jj) {
      p[jj] = __builtin_amdgcn_exp2f((-acc[jj] - gm) * L2E);
      ls += p[jj];
    }
    sm[PSUM_OFF + il * 17 + slot] = ls;
    __syncthreads();
    float tot = sm[PSUM_OFF + il * 17];
#pragma unroll
    for (int s = 1; s < 16; ++s) tot += sm[PSUM_OFF + il * 17 + s];
    const float rs = __builtin_amdgcn_rcpf(tot);
    // w_ws layout [bh][j][i]: coalesced over il
#pragma unroll
    for (int jj = 0; jj < 4; ++jj)
      w_ws[((size_t)bh * SS + j0 + jj) * SS + i0 + il] = p[jj] * rs;
  }
}

// ---- k2: ctx (contract heads, in LDS) + fc GEMV ----------------------------
// grid = (B*S/4)*2 = 512: rowblk = bid>>1 (4 rows), ehalf = bid&1 (128 e).
// block = 512, LDS 37 KB -> 2 blocks/CU.
__global__ __launch_bounds__(512) void k2(
    const float* __restrict__ w_ws, const float* __restrict__ v_ws,
    const float* __restrict__ Wfc, const float* __restrict__ bfc,
    float* __restrict__ out)
{
  __shared__ float wl[4 * 1024];   // [r][h*64+j]
  __shared__ float vl[4 * 320];    // [r][h*20+d] (stride 20: 16B-aligned)
  __shared__ float ctx[4 * 1024];  // [r][j*16+d]
  const int t = threadIdx.x;
  const int bid = blockIdx.x;
  const int rowblk = bid >> 1;
  const int ehalf = bid & 1;
  const int row0 = rowblk * 4;
  const int b = row0 >> 6;
  const int i0 = row0 & 63;
  const int e0 = ehalf * 128;

  // stage wl: f32x4 over i picks 4 rows at once ([bh][j][i] layout)
#pragma unroll
  for (int u = 0; u < 2; ++u) {
    const int idx = t + 512 * u;
    const int hh = idx >> 6;
    const int j = idx & 63;
    const f32x4 v4 = *(const f32x4*)&w_ws[(((size_t)b * HH + hh) * SS + j) * SS + i0];
    wl[0 * 1024 + hh * 64 + j] = v4[0];
    wl[1 * 1024 + hh * 64 + j] = v4[1];
    wl[2 * 1024 + hh * 64 + j] = v4[2];
    wl[3 * 1024 + hh * 64 + j] = v4[3];
  }
#pragma unroll
  for (int u = 0; u < 2; ++u) {
    const int idx = t + 512 * u;
    const int r = idx >> 8;
    const int rem = idx & 255;
    vl[r * 320 + (rem >> 4) * 20 + (rem & 15)] = v_ws[(size_t)(row0 + r) * EE + rem];
  }
  __syncthreads();

  // ctx[r][j*16+d] = sum_h wl[r][h][j] * vl[r][h][d]
  // thread: r = t>>7, j = (t>>1)&63, dh = t&1 (8 d's, two f32x4 accs)
  {
    const int r = t >> 7;
    const int j = (t >> 1) & 63;
    const int dh = t & 1;
    f32x4 a0 = {0.f, 0.f, 0.f, 0.f}, a1 = {0.f, 0.f, 0.f, 0.f};
#pragma unroll
    for (int hh = 0; hh < HH; ++hh) {
      const float wv = wl[r * 1024 + hh * 64 + j];
      const f32x4 v0 = *(const f32x4*)&vl[r * 320 + hh * 20 + dh * 8];
      const f32x4 v1 = *(const f32x4*)&vl[r * 320 + hh * 20 + dh * 8 + 4];
#pragma unroll
      for (int u = 0; u < 4; ++u) {
        a0[u] = fmaf(wv, v0[u], a0[u]);
        a1[u] = fmaf(wv, v1[u], a1[u]);
      }
    }
    *(f32x4*)&ctx[r * 1024 + j * 16 + dh * 8] = a0;
    *(f32x4*)&ctx[r * 1024 + j * 16 + dh * 8 + 4] = a1;
  }
  __syncthreads();

  // fc: thread (kg = lane&15, eg = lane>>4, wave) -> 2 passes x 2 e x 4 rows
  {
    const int wave = t >> 6;
    const int lane = t & 63;
    const int kg = lane & 15;
    const int eg = lane >> 4;
#pragma unroll
    for (int pass = 0; pass < 2; ++pass) {
      const int e = e0 + pass * 64 + wave * 8 + eg * 2;
      const float* wf0 = Wfc + (size_t)e * 1024;
      const float* wf1 = wf0 + 1024;
      float a00 = 0.f, a01 = 0.f, a10 = 0.f, a11 = 0.f;
      float a20 = 0.f, a21 = 0.f, a30 = 0.f, a31 = 0.f;
#pragma unroll 4
      for (int p = 0; p < 16; ++p) {
        const int k0 = p * 64 + kg * 4;
        const f32x4 c0 = *(const f32x4*)(ctx + k0);
        const f32x4 c1 = *(const f32x4*)(ctx + 1024 + k0);
        const f32x4 c2 = *(const f32x4*)(ctx + 2048 + k0);
        const f32x4 c3 = *(const f32x4*)(ctx + 3072 + k0);
        const f32x4 w0 = *(const f32x4*)(wf0 + k0);
        const f32x4 w1 = *(const f32x4*)(wf1 + k0);
#pragma unroll
        for (int u = 0; u < 4; ++u) {
          a00 = fmaf(c0[u], w0[u], a00);
          a01 = fmaf(c0[u], w1[u], a01);
          a10 = fmaf(c1[u], w0[u], a10);
          a11 = fmaf(c1[u], w1[u], a11);
          a20 = fmaf(c2[u], w0[u], a20);
          a21 = fmaf(c2[u], w1[u], a21);
          a30 = fmaf(c3[u], w0[u], a30);
          a31 = fmaf(c3[u], w1[u], a31);
        }
      }
#pragma unroll
      for (int msk = 1; msk <= 8; msk <<= 1) {
        a00 += __shfl_xor(a00, msk); a01 += __shfl_xor(a01, msk);
        a10 += __shfl_xor(a10, msk); a11 += __shfl_xor(a11, msk);
        a20 += __shfl_xor(a20, msk); a21 += __shfl_xor(a21, msk);
        a30 += __shfl_xor(a30, msk); a31 += __shfl_xor(a31, msk);
      }
      if (kg == 0) {
        const float b0 = bfc[e];
        const float b1 = bfc[e + 1];
        out[(size_t)(row0 + 0) * EE + e] = a00 + b0;
        out[(size_t)(row0 + 0) * EE + e + 1] = a01 + b1;
        out[(size_t)(row0 + 1) * EE + e] = a10 + b0;
        out[(size_t)(row0 + 1) * EE + e + 1] = a11 + b1;
        out[(size_t)(row0 + 2) * EE + e] = a20 + b0;
        out[(size_t)(row0 + 2) * EE + e + 1] = a21 + b1;
        out[(size_t)(row0 + 3) * EE + e] = a30 + b0;
        out[(size_t)(row0 + 3) * EE + e + 1] = a31 + b1;
      }
    }
  }
}

extern "C" void kernel_launch(void* const* d_in, const int* in_sizes, int n_in,
                              void* d_out, int out_size, void* d_ws, size_t ws_size,
                              hipStream_t stream) {
  const float* x   = (const float*)d_in[0];
  const float* Wq  = (const float*)d_in[1];
  const float* bq  = (const float*)d_in[2];
  const float* Wk  = (const float*)d_in[3];
  const float* bk  = (const float*)d_in[4];
  const float* Wv  = (const float*)d_in[5];
  const float* bv  = (const float*)d_in[6];
  const float* Wa  = (const float*)d_in[7];
  const float* ba  = (const float*)d_in[8];
  const float* av  = (const float*)d_in[9];
  const float* Wfc = (const float*)d_in[10];
  const float* bfc = (const float*)d_in[11];

  float* ws = (float*)d_ws;
  float* v_ws = ws;                                 // 262144 f32
  float* w_ws = v_ws + (size_t)BB * SS * EE;        // 1048576 f32 [bh][j][i]

  hipLaunchKernelGGL(k1, dim3(BB * HH * 2), dim3(512), 0, stream,
                     x, Wq, bq, Wk, bk, Wv, bv, Wa, ba, av, v_ws, w_ws);
  hipLaunchKernelGGL(k2, dim3(BB * SS / 2), dim3(512), 0, stream,
                     w_ws, v_ws, Wfc, bfc, (float*)d_out);
}